// Round 6
// baseline (93.905 us; speedup 1.0000x reference)
//
#include <hip/hip_runtime.h>

// DWT (Haar) forward: (16,4,1024,1024) f32 -> LL (16,4,512,512) ++ high (16,12,512,512)
//
// Memory-bound streaming kernel: 256 MiB read + 256 MiB write, zero reuse.
// R5 change: 2 ADJACENT output rows per thread -> 4 input rows within a
// 16 KB window. 4 dense 16B/lane loads (wave = 1 KB contiguous each) issued
// up front for MLP depth; 8 dense f32x2 stores (wave = 512 B contiguous).
// (R3 showed far-apart rows hurt page locality; adjacent rows avoid that.)
//
// Layout:
//   in[n][c][y][x], strides (4*1024*1024, 1024*1024, 1024, 1)
//   d_out: LL flat first (16*4*512*512 = 16,777,216 floats),
//          then high[n][k][h][w], k = [LH c0..3, HL c0..3, HH c0..3],
//          strides (12*512*512, 512*512, 512, 1), base offset 16,777,216.

typedef float f32x4 __attribute__((ext_vector_type(4)));
typedef float f32x2 __attribute__((ext_vector_type(2)));

__global__ __launch_bounds__(256) void dwt_haar_fwd(const float* __restrict__ in,
                                                    float* __restrict__ out) {
    const int t = blockIdx.x * 256 + threadIdx.x;   // [0, 2^22)

    const int w2 = t & 255;          // 2-output-col chunk, 256 per row
    const int hp = (t >> 8) & 255;   // output row PAIR: rows 2hp, 2hp+1
    const int nc = t >> 16;          // plane index n*4+c, [0,64)
    const int c  = nc & 3;
    const int n  = nc >> 2;

    // ---- input: rows 4hp..4hp+3, cols 4*w2..4*w2+3 (16B dense per lane) ----
    const size_t inOff = (((size_t)nc * 1024 + 4 * hp) * 1024) + 4 * (size_t)w2;
    const f32x4* in4 = reinterpret_cast<const f32x4*>(in + inOff);
    const f32x4 r0 = __builtin_nontemporal_load(in4 + 0);     // input row 4hp
    const f32x4 r1 = __builtin_nontemporal_load(in4 + 256);   // 4hp+1
    const f32x4 r2 = __builtin_nontemporal_load(in4 + 512);   // 4hp+2
    const f32x4 r3 = __builtin_nontemporal_load(in4 + 768);   // 4hp+3

    // ---- butterflies: output row 2hp from (r0,r1), row 2hp+1 from (r2,r3) ----
    f32x2 LL0, LH0, HL0, HH0, LL1, LH1, HL1, HH1;
    {
        const float s01_0 = r0.x + r0.y, d01_0 = r0.x - r0.y;
        const float s23_0 = r1.x + r1.y, d23_0 = r1.x - r1.y;
        const float s01_1 = r0.z + r0.w, d01_1 = r0.z - r0.w;
        const float s23_1 = r1.z + r1.w, d23_1 = r1.z - r1.w;
        LL0.x = (s01_0 + s23_0) * 0.5f;  LH0.x = (s01_0 - s23_0) * 0.5f;
        HL0.x = (d01_0 + d23_0) * 0.5f;  HH0.x = (d01_0 - d23_0) * 0.5f;
        LL0.y = (s01_1 + s23_1) * 0.5f;  LH0.y = (s01_1 - s23_1) * 0.5f;
        HL0.y = (d01_1 + d23_1) * 0.5f;  HH0.y = (d01_1 - d23_1) * 0.5f;
    }
    {
        const float s01_0 = r2.x + r2.y, d01_0 = r2.x - r2.y;
        const float s23_0 = r3.x + r3.y, d23_0 = r3.x - r3.y;
        const float s01_1 = r2.z + r2.w, d01_1 = r2.z - r2.w;
        const float s23_1 = r3.z + r3.w, d23_1 = r3.z - r3.w;
        LL1.x = (s01_0 + s23_0) * 0.5f;  LH1.x = (s01_0 - s23_0) * 0.5f;
        HL1.x = (d01_0 + d23_0) * 0.5f;  HH1.x = (d01_0 - d23_0) * 0.5f;
        LL1.y = (s01_1 + s23_1) * 0.5f;  LH1.y = (s01_1 - s23_1) * 0.5f;
        HL1.y = (d01_1 + d23_1) * 0.5f;  HH1.y = (d01_1 - d23_1) * 0.5f;
    }

    // ---- output ----
    const size_t llOff = (((size_t)nc * 512 + 2 * hp) * 512) + 2 * (size_t)w2;
    const size_t hiRow = (((size_t)(n * 12 + c) * 512 + 2 * hp) * 512) + 2 * (size_t)w2
                         + (size_t)16777216;               // high starts after LL
    // HL +4 channels, HH +8 channels: 4*512*512 = 1,048,576 floats apart
    __builtin_nontemporal_store(LL0, reinterpret_cast<f32x2*>(out + llOff));
    __builtin_nontemporal_store(LL1, reinterpret_cast<f32x2*>(out + llOff + 512));
    __builtin_nontemporal_store(LH0, reinterpret_cast<f32x2*>(out + hiRow));
    __builtin_nontemporal_store(LH1, reinterpret_cast<f32x2*>(out + hiRow + 512));
    __builtin_nontemporal_store(HL0, reinterpret_cast<f32x2*>(out + hiRow + 1048576));
    __builtin_nontemporal_store(HL1, reinterpret_cast<f32x2*>(out + hiRow + 1048576 + 512));
    __builtin_nontemporal_store(HH0, reinterpret_cast<f32x2*>(out + hiRow + 2097152));
    __builtin_nontemporal_store(HH1, reinterpret_cast<f32x2*>(out + hiRow + 2097152 + 512));
}

extern "C" void kernel_launch(void* const* d_in, const int* in_sizes, int n_in,
                              void* d_out, int out_size, void* d_ws, size_t ws_size,
                              hipStream_t stream) {
    const float* in = (const float*)d_in[0];
    float* out = (float*)d_out;
    const int threads = 256;
    const int blocks  = (16 * 4 * 512 * 512 / 4) / threads;   // 16384
    dwt_haar_fwd<<<blocks, threads, 0, stream>>>(in, out);
}

// Round 7
// 92.457 us; speedup vs baseline: 1.0157x; 1.0157x over previous
//
#include <hip/hip_runtime.h>

// DWT (Haar) forward: (16,4,1024,1024) f32 -> LL (16,4,512,512) ++ high (16,12,512,512)
//
// FINAL (R4 mapping, best measured 92.1 us = 5.83 TB/s = 93% of the 6.29 TB/s
// measured copy ceiling). Memory-bound: 256 MiB read + 256 MiB write, zero
// reuse. 2 output pixels per thread so every load instruction is FULLY dense:
// lane i reads one 16B chunk at lane-stride 16B (wave = 1 KB contiguous,
// each 128B line touched exactly once). Stores are 8B/lane (f32x2), wave =
// 512B contiguous full lines per subband stream.
//
// Explored and rejected:
//   R2: nontemporal hints          -> neutral (kept, harmless)
//   R3: 4x rows/thread, 128 apart  -> -7% (page locality loss)
//   R5: 2 adjacent rows/thread     -> -2% (MLP not the limiter)
//
// Layout:
//   in[n][c][y][x], strides (4*1024*1024, 1024*1024, 1024, 1)
//   d_out: LL flat first (16*4*512*512 = 16,777,216 floats),
//          then high[n][k][h][w], k = [LH c0..3, HL c0..3, HH c0..3],
//          strides (12*512*512, 512*512, 512, 1), base offset 16,777,216.

typedef float f32x4 __attribute__((ext_vector_type(4)));
typedef float f32x2 __attribute__((ext_vector_type(2)));

__global__ __launch_bounds__(256) void dwt_haar_fwd(const float* __restrict__ in,
                                                    float* __restrict__ out) {
    const int t = blockIdx.x * 256 + threadIdx.x;   // [0, 2^23)

    const int w2 = t & 255;          // 2-output-col chunk, 256 per row
    const int h  = (t >> 8) & 511;   // output row
    const int nc = t >> 17;          // plane index n*4+c, [0,64)
    const int c  = nc & 3;
    const int n  = nc >> 2;

    // ---- input: rows 2h, 2h+1, cols 4*w2 .. 4*w2+3 (16B dense per lane) ----
    const size_t inOff = (((size_t)nc * 1024 + 2 * h) * 1024) + 4 * (size_t)w2;
    const f32x4* in4 = reinterpret_cast<const f32x4*>(in + inOff);
    const f32x4 r0 = __builtin_nontemporal_load(in4 + 0);     // row 2h
    const f32x4 r1 = __builtin_nontemporal_load(in4 + 256);   // row 2h+1

    // ---- butterfly: pixel0 = cols(2w2), pixel1 = cols(2w2+1) ----
    f32x2 LL, LH, HL, HH;
    {
        const float s01_0 = r0.x + r0.y, d01_0 = r0.x - r0.y;
        const float s23_0 = r1.x + r1.y, d23_0 = r1.x - r1.y;
        const float s01_1 = r0.z + r0.w, d01_1 = r0.z - r0.w;
        const float s23_1 = r1.z + r1.w, d23_1 = r1.z - r1.w;

        LL.x = (s01_0 + s23_0) * 0.5f;  LH.x = (s01_0 - s23_0) * 0.5f;
        HL.x = (d01_0 + d23_0) * 0.5f;  HH.x = (d01_0 - d23_0) * 0.5f;
        LL.y = (s01_1 + s23_1) * 0.5f;  LH.y = (s01_1 - s23_1) * 0.5f;
        HL.y = (d01_1 + d23_1) * 0.5f;  HH.y = (d01_1 - d23_1) * 0.5f;
    }

    // ---- output ----
    const size_t llOff = (((size_t)nc * 512 + h) * 512) + 2 * (size_t)w2;
    const size_t hiRow = (((size_t)(n * 12 + c) * 512 + h) * 512) + 2 * (size_t)w2
                         + (size_t)16777216;               // high starts after LL
    // HL +4 channels, HH +8 channels: 4*512*512 = 1,048,576 floats apart
    __builtin_nontemporal_store(LL, reinterpret_cast<f32x2*>(out + llOff));
    __builtin_nontemporal_store(LH, reinterpret_cast<f32x2*>(out + hiRow));
    __builtin_nontemporal_store(HL, reinterpret_cast<f32x2*>(out + hiRow + 1048576));
    __builtin_nontemporal_store(HH, reinterpret_cast<f32x2*>(out + hiRow + 2097152));
}

extern "C" void kernel_launch(void* const* d_in, const int* in_sizes, int n_in,
                              void* d_out, int out_size, void* d_ws, size_t ws_size,
                              hipStream_t stream) {
    const float* in = (const float*)d_in[0];
    float* out = (float*)d_out;
    const int threads = 256;
    const int blocks  = (16 * 4 * 512 * 512 / 2) / threads;   // 32768
    dwt_haar_fwd<<<blocks, threads, 0, stream>>>(in, out);
}